// Round 3
// baseline (530.857 us; speedup 1.0000x reference)
//
#include <hip/hip_runtime.h>
#include <stdint.h>

#define NB 4
#define NN 128
#define NP 512
#define NJ 640
#define HD 64
#define ED 32

// out element offsets (f32): upd_q[2048], upd_x[1536], tor[7168], o[32768]
#define OFF_Q 0
#define OFF_X 2048
#define OFF_T 3584
#define OFF_O 10752

// ---------------------------------------------------------------------------
// Kernel 1: precompute Hall[b,j,t] = all_h @ Wm1[64:128], Hi[b,i,t] = h @ Wm1[0:64] + bm1,
//           AQ (all_q), NQ (normalized all_q), AX (all_x)
// grid = NB*NJ + NB*NN blocks of 64 threads
// ---------------------------------------------------------------------------
__global__ void __launch_bounds__(64)
precompute_kernel(const float* __restrict__ q, const float* __restrict__ x,
                  const float* __restrict__ h, const float* __restrict__ pq,
                  const float* __restrict__ px, const float* __restrict__ ph,
                  const float* __restrict__ Wm1, const float* __restrict__ bm1,
                  float* __restrict__ Hall, float* __restrict__ Hi,
                  float* __restrict__ AQ, float* __restrict__ NQ,
                  float* __restrict__ AX)
{
  int blk = blockIdx.x;
  int t = threadIdx.x;
  if (blk < NB * NJ) {
    int b = blk / NJ, j = blk % NJ;
    const float* hrow = (j < NN) ? (h + (size_t)(b * NN + j) * HD)
                                 : (ph + (size_t)(b * NP + (j - NN)) * HD);
    float acc0 = 0.f, acc1 = 0.f;
#pragma unroll
    for (int k = 0; k < HD; k += 2) {
      acc0 += hrow[k]     * Wm1[(64 + k) * 64 + t];
      acc1 += hrow[k + 1] * Wm1[(65 + k) * 64 + t];
    }
    Hall[(size_t)(b * NJ + j) * 64 + t] = acc0 + acc1;
    if (t < 4) {
      const float* qrow = (j < NN) ? (q + (size_t)(b * NN + j) * 4)
                                   : (pq + (size_t)(b * NP + (j - NN)) * 4);
      float q0 = qrow[0], q1 = qrow[1], q2 = qrow[2], q3 = qrow[3];
      float comp = (t == 0) ? q0 : (t == 1) ? q1 : (t == 2) ? q2 : q3;
      AQ[(size_t)(b * NJ + j) * 4 + t] = comp;
      float n = fmaxf(sqrtf(q0 * q0 + q1 * q1 + q2 * q2 + q3 * q3), 1e-12f);
      NQ[(size_t)(b * NJ + j) * 4 + t] = comp / n;
    }
    if (t < 3) {
      const float* xrow = (j < NN) ? (x + (size_t)(b * NN + j) * 3)
                                   : (px + (size_t)(b * NP + (j - NN)) * 3);
      AX[(size_t)(b * NJ + j) * 3 + t] = xrow[t];
    }
  } else {
    int idx = blk - NB * NJ;
    int b = idx / NN, i = idx % NN;
    const float* hrow = h + (size_t)(b * NN + i) * HD;
    float acc = bm1[t];
#pragma unroll
    for (int k = 0; k < HD; ++k) acc += hrow[k] * Wm1[k * 64 + t];
    Hi[(size_t)(b * NN + i) * 64 + t] = acc;
  }
}

// ---------------------------------------------------------------------------
// Kernel 2: fused edge loop + node epilogue. One block per (b,i); 4 waves,
// lane = hidden index t. grid = NB*NN = 512, block = 256.
// ---------------------------------------------------------------------------
__global__ void __launch_bounds__(256)
egnn_main(const float* __restrict__ q, const float* __restrict__ x,
          const float* __restrict__ h, const float* __restrict__ e,
          const float* __restrict__ pe,
          const float* __restrict__ Wm1, const float* __restrict__ Wm2,
          const float* __restrict__ bm2, const float* __restrict__ Wx1,
          const float* __restrict__ bx1, const float* __restrict__ Wx2,
          const float* __restrict__ bx2, const float* __restrict__ Wf1,
          const float* __restrict__ bf1, const float* __restrict__ Wf2,
          const float* __restrict__ bf2_, const float* __restrict__ Wq1,
          const float* __restrict__ bq1, const float* __restrict__ Wq2,
          const float* __restrict__ bq2, const float* __restrict__ Wt1,
          const float* __restrict__ bt1, const float* __restrict__ Wt2,
          const float* __restrict__ bt2,
          const float* __restrict__ Hall, const float* __restrict__ Hi,
          const float* __restrict__ AQ, const float* __restrict__ NQ,
          const float* __restrict__ AX, float* __restrict__ out)
{
  __shared__ float sW1[41 * 64];      // Wm1 rows 128..168, [kk][t]
  __shared__ float sW2[64 * 64];      // [k][t]
  __shared__ float sWx1[64 * 64];     // [k][t]
  __shared__ float sWx2[64 * 3];      // [t][c]
  __shared__ float sbm2[64], sbx1[64], sbx2[3];
  __shared__ float4 sA4[4][16];       // per-wave a1
  __shared__ float4 sB4[4][16];       // per-wave m
  __shared__ float sMsum[4][64];
  __shared__ float sDx[4][3];
  __shared__ float sHi64[64];         // h_i
  __shared__ float sPh3[4][64];       // phase-3 scratch per wave

  int b = blockIdx.x >> 7;
  int i = blockIdx.x & 127;
  int tid = threadIdx.x;
  int wid = tid >> 6;
  int lane = tid & 63;
  float* sAf = (float*)sA4;
  float* sBf = (float*)sB4;

  // ---- stage weights to LDS ----
  for (int idx = tid; idx < 41 * 64; idx += 256) sW1[idx] = Wm1[128 * 64 + idx];
  for (int idx = tid; idx < 4096; idx += 256) sW2[idx]  = Wm2[idx];
  for (int idx = tid; idx < 4096; idx += 256) sWx1[idx] = Wx1[idx];
  if (tid < 192) sWx2[tid] = Wx2[tid];
  if (tid < 64) { sbm2[tid] = bm2[tid]; sbx1[tid] = bx1[tid]; }
  if (tid < 3) sbx2[tid] = bx2[tid];
  if (tid < 64) sHi64[tid] = h[(size_t)(b * NN + i) * 64 + tid];
  __syncthreads();

  // per-node scalars (all threads)
  const float* qrow = q + (size_t)(b * NN + i) * 4;
  float qi0 = qrow[0], qi1 = qrow[1], qi2 = qrow[2], qi3 = qrow[3];
  const float* xrow = x + (size_t)(b * NN + i) * 3;
  float xi0 = xrow[0], xi1 = xrow[1], xi2 = xrow[2];
  float hi_reg = Hi[(size_t)(b * NN + i) * 64 + lane];

  float msum_l = 0.f;
  float dxs0 = 0.f, dxs1 = 0.f, dxs2 = 0.f;

  for (int j = wid; j < NJ; j += 4) {
    if (j == i) continue;  // diagonal mask (wave-uniform)

    // ---- e row (32 f32, broadcast across lanes) ----
    const float* erow = (j < NN)
        ? (e + ((size_t)(b * NN + i) * NN + j) * ED)
        : (pe + ((size_t)(b * NN + i) * NP + (j - NN)) * ED);
    const float4* e4 = reinterpret_cast<const float4*>(erow);
    float ef[32];
#pragma unroll
    for (int kk = 0; kk < 8; ++kk) {
      float4 v = e4[kk];
      ef[kk * 4 + 0] = v.x; ef[kk * 4 + 1] = v.y;
      ef[kk * 4 + 2] = v.z; ef[kk * 4 + 3] = v.w;
    }

    // ---- geometry (all lanes redundantly) ----
    const float* xjp = AX + (size_t)(b * NJ + j) * 3;
    float xj0 = xjp[0], xj1 = xjp[1], xj2 = xjp[2];
    float4 qj = *reinterpret_cast<const float4*>(AQ + (size_t)(b * NJ + j) * 4);
    float4 nq = *reinterpret_cast<const float4*>(NQ + (size_t)(b * NJ + j) * 4);
    float d0 = xi0 - xj0, d1 = xi1 - xj1, d2v = xi2 - xj2;
    float d2 = d0 * d0 + d1 * d1 + d2v * d2v;
    float qdot = fabsf(qi0 * qj.x + qi1 * qj.y + qi2 * qj.z + qi3 * qj.w);
    float ajw = qj.x, ajx = -qj.y, ajy = -qj.z, ajz = -qj.w;  // conj
    float t0 = 2.f * (ajy * d2v - ajz * d1);
    float t1 = 2.f * (ajz * d0 - ajx * d2v);
    float t2 = 2.f * (ajx * d1 - ajy * d0);
    float lx0 = d0 + ajw * t0 + (ajy * t2 - ajz * t1);
    float lx1 = d1 + ajw * t1 + (ajz * t0 - ajx * t2);
    float lx2 = d2v + ajw * t2 + (ajx * t1 - ajy * t0);
    float lqw = ajw * qi0 - ajx * qi1 - ajy * qi2 - ajz * qi3;
    float lqx = ajw * qi1 + ajx * qi0 + ajy * qi3 - ajz * qi2;
    float lqy = ajw * qi2 - ajx * qi3 + ajy * qi0 + ajz * qi1;
    float lqz = ajw * qi3 + ajx * qi2 - ajy * qi1 + ajz * qi0;

    // ---- layer 1: a1[t] = relu(Hi + Hall[j] + e@W + geo@W) ----
    float acc0 = hi_reg + Hall[(size_t)(b * NJ + j) * 64 + lane];
    float acc1 = 0.f, acc2 = 0.f, acc3 = 0.f;
#pragma unroll
    for (int k = 0; k < 32; k += 4) {
      acc0 += ef[k]     * sW1[(k)     * 64 + lane];
      acc1 += ef[k + 1] * sW1[(k + 1) * 64 + lane];
      acc2 += ef[k + 2] * sW1[(k + 2) * 64 + lane];
      acc3 += ef[k + 3] * sW1[(k + 3) * 64 + lane];
    }
    acc0 += lx0 * sW1[32 * 64 + lane];
    acc1 += lx1 * sW1[33 * 64 + lane];
    acc2 += lx2 * sW1[34 * 64 + lane];
    acc3 += lqw * sW1[35 * 64 + lane];
    acc0 += lqx * sW1[36 * 64 + lane];
    acc1 += lqy * sW1[37 * 64 + lane];
    acc2 += lqz * sW1[38 * 64 + lane];
    acc3 += d2  * sW1[39 * 64 + lane];
    acc0 += qdot * sW1[40 * 64 + lane];
    float a1 = fmaxf(acc0 + acc1 + acc2 + acc3, 0.f);

    // ---- layer 2: m[t] ----
    sAf[wid * 64 + lane] = a1;
    float m0 = sbm2[lane], m1 = 0.f, m2 = 0.f, m3 = 0.f;
#pragma unroll
    for (int kq = 0; kq < 16; ++kq) {
      float4 av = sA4[wid][kq];
      int kb = kq * 256 + lane;
      m0 += av.x * sW2[kb];
      m1 += av.y * sW2[kb + 64];
      m2 += av.z * sW2[kb + 128];
      m3 += av.w * sW2[kb + 192];
    }
    float mval = m0 + m1 + m2 + m3;
    msum_l += mval;

    // ---- dx MLP: x1 = relu(m@Wx1+bx1); dx = x1@Wx2+bx2 ----
    sBf[wid * 64 + lane] = mval;
    float x0a = sbx1[lane], x1a = 0.f, x2a = 0.f, x3a = 0.f;
#pragma unroll
    for (int kq = 0; kq < 16; ++kq) {
      float4 mv = sB4[wid][kq];
      int kb = kq * 256 + lane;
      x0a += mv.x * sWx1[kb];
      x1a += mv.y * sWx1[kb + 64];
      x2a += mv.z * sWx1[kb + 128];
      x3a += mv.w * sWx1[kb + 192];
    }
    float x1v = fmaxf(x0a + x1a + x2a + x3a, 0.f);
    float p0 = x1v * sWx2[lane * 3 + 0];
    float p1 = x1v * sWx2[lane * 3 + 1];
    float p2 = x1v * sWx2[lane * 3 + 2];
#pragma unroll
    for (int off = 32; off >= 1; off >>= 1) {
      p0 += __shfl_xor(p0, off);
      p1 += __shfl_xor(p1, off);
      p2 += __shfl_xor(p2, off);
    }
    float dxc0 = p0 + sbx2[0], dxc1 = p1 + sbx2[1], dxc2 = p2 + sbx2[2];

    // rotate by normalized q_j, accumulate
    float rw = nq.x, rx = nq.y, ry = nq.z, rz = nq.w;
    float rt0 = 2.f * (ry * dxc2 - rz * dxc1);
    float rt1 = 2.f * (rz * dxc0 - rx * dxc2);
    float rt2 = 2.f * (rx * dxc1 - ry * dxc0);
    dxs0 += dxc0 + rw * rt0 + (ry * rt2 - rz * rt1);
    dxs1 += dxc1 + rw * rt1 + (rz * rt0 - rx * rt2);
    dxs2 += dxc2 + rw * rt2 + (rx * rt1 - ry * rt0);
  }

  sMsum[wid][lane] = msum_l;
  if (lane == 0) { sDx[wid][0] = dxs0; sDx[wid][1] = dxs1; sDx[wid][2] = dxs2; }
  __syncthreads();

  // ---- phase 3: per-node epilogues, one wave each ----
  size_t node = (size_t)(b * NN + i);
  if (wid == 0) {
    // o = relu([h,msum]@Wf1+bf1)@Wf2+bf2
    float ms = sMsum[0][lane] + sMsum[1][lane] + sMsum[2][lane] + sMsum[3][lane];
    sPh3[0][lane] = ms;
    float f1a = bf1[lane], f1b = 0.f;
#pragma unroll 8
    for (int k = 0; k < 64; ++k) {
      f1a += sHi64[k]   * Wf1[k * 64 + lane];
      f1b += sPh3[0][k] * Wf1[(64 + k) * 64 + lane];
    }
    float f1 = fmaxf(f1a + f1b, 0.f);
    sPh3[0][lane] = f1;
    float oacc = bf2_[lane];
#pragma unroll 8
    for (int k = 0; k < 64; ++k) oacc += sPh3[0][k] * Wf2[k * 64 + lane];
    out[OFF_O + node * 64 + lane] = oacc;
  } else if (wid == 1) {
    // upd_q = normalize(quat_mul(q, normalize(msum-MLP)))
    float ms = sMsum[0][lane] + sMsum[1][lane] + sMsum[2][lane] + sMsum[3][lane];
    sPh3[1][lane] = ms;
    float a = bq1[lane];
#pragma unroll 8
    for (int k = 0; k < 64; ++k) a += sPh3[1][k] * Wq1[k * 64 + lane];
    a = fmaxf(a, 0.f);
    float p0 = a * Wq2[lane * 4 + 0];
    float p1 = a * Wq2[lane * 4 + 1];
    float p2 = a * Wq2[lane * 4 + 2];
    float p3 = a * Wq2[lane * 4 + 3];
#pragma unroll
    for (int off = 32; off >= 1; off >>= 1) {
      p0 += __shfl_xor(p0, off);
      p1 += __shfl_xor(p1, off);
      p2 += __shfl_xor(p2, off);
      p3 += __shfl_xor(p3, off);
    }
    float dq0 = p0 + bq2[0];
    float dq1 = p1 + bq2[1];
    float dq2 = p2 + bq2[2];
    float dq3 = p3 + bq2[3];
    float n = fmaxf(sqrtf(dq0 * dq0 + dq1 * dq1 + dq2 * dq2 + dq3 * dq3), 1e-12f);
    dq0 /= n; dq1 /= n; dq2 /= n; dq3 /= n;
    float uw = qi0 * dq0 - qi1 * dq1 - qi2 * dq2 - qi3 * dq3;
    float ux = qi0 * dq1 + qi1 * dq0 + qi2 * dq3 - qi3 * dq2;
    float uy = qi0 * dq2 - qi1 * dq3 + qi2 * dq0 + qi3 * dq1;
    float uz = qi0 * dq3 + qi1 * dq2 - qi2 * dq1 + qi3 * dq0;
    float n2 = fmaxf(sqrtf(uw * uw + ux * ux + uy * uy + uz * uz), 1e-12f);
    if (lane == 0) {
      float* po = out + OFF_Q + node * 4;
      po[0] = uw / n2; po[1] = ux / n2;
      po[2] = uy / n2; po[3] = uz / n2;
    }
  } else if (wid == 2) {
    // torsions: normalize pairs of msum-MLP(14)
    float ms = sMsum[0][lane] + sMsum[1][lane] + sMsum[2][lane] + sMsum[3][lane];
    sPh3[2][lane] = ms;
    float a = bt1[lane];
#pragma unroll 8
    for (int k = 0; k < 64; ++k) a += sPh3[2][k] * Wt1[k * 64 + lane];
    a = fmaxf(a, 0.f);
    sPh3[2][lane] = a;
    if (lane < 14) {
      float v = bt2[lane];
#pragma unroll 8
      for (int k = 0; k < 64; ++k) v += sPh3[2][k] * Wt2[k * 14 + lane];
      float pv = __shfl_xor(v, 1);
      float nrm = fmaxf(sqrtf(v * v + pv * pv), 1e-12f);
      out[OFF_T + node * 14 + lane] = v / nrm;
    }
  } else {
    // upd_x = x + dxsum/639
    if (lane < 3) {
      float xs = sDx[0][lane] + sDx[1][lane] + sDx[2][lane] + sDx[3][lane];
      float xiv = (lane == 0) ? xi0 : (lane == 1) ? xi1 : xi2;
      out[OFF_X + node * 3 + lane] = xiv + xs / 639.0f;
    }
  }
}

extern "C" void kernel_launch(void* const* d_in, const int* in_sizes, int n_in,
                              void* d_out, int out_size, void* d_ws, size_t ws_size,
                              hipStream_t stream) {
  const float* q   = (const float*)d_in[0];
  const float* x   = (const float*)d_in[1];
  const float* h   = (const float*)d_in[3];
  const float* e   = (const float*)d_in[4];
  const float* pq  = (const float*)d_in[6];
  const float* px  = (const float*)d_in[7];
  const float* pe  = (const float*)d_in[8];
  const float* ph  = (const float*)d_in[9];
  const float* Wm1 = (const float*)d_in[11];
  const float* bm1 = (const float*)d_in[12];
  const float* Wm2 = (const float*)d_in[13];
  const float* bm2 = (const float*)d_in[14];
  const float* Wf1 = (const float*)d_in[15];
  const float* bf1 = (const float*)d_in[16];
  const float* Wf2 = (const float*)d_in[17];
  const float* bf2_ = (const float*)d_in[18];
  const float* Wx1 = (const float*)d_in[19];
  const float* bx1 = (const float*)d_in[20];
  const float* Wx2 = (const float*)d_in[21];
  const float* bx2 = (const float*)d_in[22];
  const float* Wq1 = (const float*)d_in[23];
  const float* bq1 = (const float*)d_in[24];
  const float* Wq2 = (const float*)d_in[25];
  const float* bq2 = (const float*)d_in[26];
  const float* Wt1 = (const float*)d_in[27];
  const float* bt1 = (const float*)d_in[28];
  const float* Wt2 = (const float*)d_in[29];
  const float* bt2 = (const float*)d_in[30];

  float* ws = (float*)d_ws;
  float* Hall = ws;                 // 4*640*64   = 163840
  float* Hi   = ws + 163840;        // 4*128*64   = 32768
  float* AQ   = ws + 196608;        // 4*640*4    = 10240
  float* NQ   = ws + 206848;        // 4*640*4    = 10240
  float* AX   = ws + 217088;        // 4*640*3    = 7680

  precompute_kernel<<<NB * NJ + NB * NN, 64, 0, stream>>>(
      q, x, h, pq, px, ph, Wm1, bm1, Hall, Hi, AQ, NQ, AX);

  egnn_main<<<NB * NN, 256, 0, stream>>>(
      q, x, h, e, pe, Wm1, Wm2, bm2, Wx1, bx1, Wx2, bx2,
      Wf1, bf1, Wf2, bf2_, Wq1, bq1, Wq2, bq2, Wt1, bt1, Wt2, bt2,
      Hall, Hi, AQ, NQ, AX, (float*)d_out);
}

// Round 4
// 222.834 us; speedup vs baseline: 2.3823x; 2.3823x over previous
//
#include <hip/hip_runtime.h>
#include <stdint.h>

#define NB 4
#define NN 128
#define NP 512
#define NJ 640
#define HD 64
#define ED 32

typedef unsigned short u16;
typedef __attribute__((ext_vector_type(8))) short short8;
typedef __attribute__((ext_vector_type(4))) float f32x4;

// out element offsets (f32): upd_q[2048], upd_x[1536], tor[7168], o[32768]
#define OFF_Q 0
#define OFF_X 2048
#define OFF_T 3584
#define OFF_O 10752

__device__ __forceinline__ u16 f2bf(float f) {
  union { float f; uint32_t i; } v; v.f = f;
  uint32_t x = v.i;
  return (u16)((x + 0x7FFFu + ((x >> 16) & 1u)) >> 16);
}
__device__ __forceinline__ uint32_t pk2(float a, float b) {
  return (uint32_t)f2bf(a) | ((uint32_t)f2bf(b) << 16);
}

// One block per (b,i). 4 waves, 10 edge-tiles of 16 each.
// F layout (bf16, Kpad=136 shorts, 272B rows): k0..31=e, k32..34=lx, k35..38=lq,
// k39=d2, k40=qdot, k41..47=0, k48..111=h_j, k112..127=0 (W rows also 0 there).
__global__ void __launch_bounds__(256, 2)
egnn_fused(const float* __restrict__ q, const float* __restrict__ x,
           const float* __restrict__ h, const float* __restrict__ e,
           const float* __restrict__ pe, const float* __restrict__ pq,
           const float* __restrict__ px, const float* __restrict__ ph,
           const float* __restrict__ Wm1, const float* __restrict__ bm1,
           const float* __restrict__ Wm2, const float* __restrict__ bm2,
           const float* __restrict__ Wx1, const float* __restrict__ bx1,
           const float* __restrict__ Wx2, const float* __restrict__ bx2,
           const float* __restrict__ Wf1, const float* __restrict__ bf1,
           const float* __restrict__ Wf2, const float* __restrict__ bf2_,
           const float* __restrict__ Wq1, const float* __restrict__ bq1,
           const float* __restrict__ Wq2, const float* __restrict__ bq2,
           const float* __restrict__ Wt1, const float* __restrict__ bt1,
           const float* __restrict__ Wt2, const float* __restrict__ bt2,
           float* __restrict__ out)
{
  __shared__ u16 sF[4][16 * 136];     // per-wave feature tile
  __shared__ u16 sT[4][16 * 72];      // per-wave a1/m/x1 transform buffer
  __shared__ float sDxT[4][16][4];
  __shared__ float sMsum[4][64];
  __shared__ float sDx[4][3];
  __shared__ float sHi64[64];
  __shared__ float sHiP[64];          // Hi = h_i@Wm1[0:64]+bm1
  __shared__ float sPh3[4][64];

  const int b = blockIdx.x >> 7;
  const int i = blockIdx.x & 127;
  const int tid = threadIdx.x;
  const int wid = tid >> 6;
  const int lane = tid & 63;
  const int nl = lane & 15;
  const int quad = lane >> 4;
  const size_t node = (size_t)(b * NN + i);

  u16* sFw = sF[wid];
  u16* sTw = sT[wid];

  // zero own F (covers pad columns; live regions rewritten per tile)
  for (int idx = lane; idx < 16 * 136 / 2; idx += 64) ((uint32_t*)sFw)[idx] = 0;

  if (tid < 64) sHi64[tid] = h[node * HD + tid];
  if (tid >= 64 && tid < 128) {
    int col = tid - 64;
    float acc = bm1[col];
#pragma unroll 8
    for (int k = 0; k < HD; ++k) acc += h[node * HD + k] * Wm1[k * 64 + col];
    sHiP[col] = acc;
  }

  const float* qr0 = q + node * 4;
  const float qi0 = qr0[0], qi1 = qr0[1], qi2 = qr0[2], qi3 = qr0[3];
  const float* xr0 = x + node * 3;
  const float xi0 = xr0[0], xi1 = xr0[1], xi2 = xr0[2];

  // ---- weight fragments in registers (B-layout: lane holds W[k=quad*8+jj][n=nl]) ----
  short8 W1f[4][4], W2f[4][2], Wx1f[4][2], Wx2f[2];
#pragma unroll
  for (int nt = 0; nt < 4; ++nt)
#pragma unroll
    for (int ks = 0; ks < 4; ++ks) {
      short8 v;
#pragma unroll
      for (int jj = 0; jj < 8; ++jj) {
        int k = ks * 32 + quad * 8 + jj;
        int row;
        if (k < 32) row = 128 + k;
        else if (k < 35) row = 160 + (k - 32);
        else if (k < 39) row = 163 + (k - 35);
        else if (k == 39) row = 167;
        else if (k == 40) row = 168;
        else if (k < 48) row = -1;
        else if (k < 112) row = 64 + (k - 48);
        else row = -1;
        v[jj] = (row < 0) ? (short)0
                          : (short)f2bf(Wm1[(size_t)row * 64 + nt * 16 + nl]);
      }
      W1f[nt][ks] = v;
    }
#pragma unroll
  for (int nt = 0; nt < 4; ++nt)
#pragma unroll
    for (int ks = 0; ks < 2; ++ks) {
      short8 v, w;
#pragma unroll
      for (int jj = 0; jj < 8; ++jj) {
        int k = ks * 32 + quad * 8 + jj;
        v[jj] = (short)f2bf(Wm2[(size_t)k * 64 + nt * 16 + nl]);
        w[jj] = (short)f2bf(Wx1[(size_t)k * 64 + nt * 16 + nl]);
      }
      W2f[nt][ks] = v;
      Wx1f[nt][ks] = w;
    }
#pragma unroll
  for (int ks = 0; ks < 2; ++ks) {
    short8 v;
#pragma unroll
    for (int jj = 0; jj < 8; ++jj) {
      int k = ks * 32 + quad * 8 + jj;
      v[jj] = (nl < 3) ? (short)f2bf(Wx2[(size_t)k * 3 + nl]) : (short)0;
    }
    Wx2f[ks] = v;
  }

  __syncthreads();  // sHiP / sHi64 ready

  float HiF[4], bm2F[4], bx1F[4];
#pragma unroll
  for (int nt = 0; nt < 4; ++nt) {
    HiF[nt] = sHiP[nt * 16 + nl];
    bm2F[nt] = bm2[nt * 16 + nl];
    bx1F[nt] = bx1[nt * 16 + nl];
  }
  const float bx2F = (nl < 3) ? bx2[nl] : 0.f;

  f32x4 msum[4];
#pragma unroll
  for (int nt = 0; nt < 4; ++nt) msum[nt] = (f32x4){0.f, 0.f, 0.f, 0.f};
  float dxs0 = 0.f, dxs1 = 0.f, dxs2 = 0.f;
  float nqw = 0.f, nqx = 0.f, nqy = 0.f, nqz = 0.f;

  for (int tile = wid; tile < 40; tile += 4) {
    const int jb = tile * 16;
    // ---- build F (wave-private LDS; no block barrier needed) ----
    {
      int er = lane >> 2, c = lane & 3;
      int jr = jb + er;
      const float* ebase = (jr < NN)
          ? e + ((node * NN) + jr) * ED + c * 8
          : pe + ((node * NP) + (jr - NN)) * ED + c * 8;
      float4 e0 = *(const float4*)ebase;
      float4 e1 = *(const float4*)(ebase + 4);
      uint4 pw;
      pw.x = pk2(e0.x, e0.y); pw.y = pk2(e0.z, e0.w);
      pw.z = pk2(e1.x, e1.y); pw.w = pk2(e1.z, e1.w);
      *(uint4*)&sFw[er * 136 + c * 8] = pw;

      const float* hb = (jr < NN) ? h + ((size_t)(b * NN + jr)) * HD + c * 16
                                  : ph + ((size_t)(b * NP + (jr - NN))) * HD + c * 16;
      float4 h0 = *(const float4*)hb, h1 = *(const float4*)(hb + 4);
      float4 h2 = *(const float4*)(hb + 8), h3 = *(const float4*)(hb + 12);
      uint4 pa, pb;
      pa.x = pk2(h0.x, h0.y); pa.y = pk2(h0.z, h0.w);
      pa.z = pk2(h1.x, h1.y); pa.w = pk2(h1.z, h1.w);
      pb.x = pk2(h2.x, h2.y); pb.y = pk2(h2.z, h2.w);
      pb.z = pk2(h3.x, h3.y); pb.w = pk2(h3.z, h3.w);
      *(uint4*)&sFw[er * 136 + 48 + c * 16] = pa;
      *(uint4*)&sFw[er * 136 + 56 + c * 16] = pb;

      if (lane < 16) {
        int j = jb + lane;
        const float* qr = (j < NN) ? q + ((size_t)(b * NN + j)) * 4
                                   : pq + ((size_t)(b * NP + (j - NN))) * 4;
        float4 qj = *(const float4*)qr;
        const float* xr = (j < NN) ? x + ((size_t)(b * NN + j)) * 3
                                   : px + ((size_t)(b * NP + (j - NN))) * 3;
        float xj0 = xr[0], xj1 = xr[1], xj2 = xr[2];
        float d0 = xi0 - xj0, d1 = xi1 - xj1, d2v = xi2 - xj2;
        float d2 = d0 * d0 + d1 * d1 + d2v * d2v;
        float qdot = fabsf(qi0 * qj.x + qi1 * qj.y + qi2 * qj.z + qi3 * qj.w);
        float ajw = qj.x, ajx = -qj.y, ajy = -qj.z, ajz = -qj.w;  // conj
        float t0 = 2.f * (ajy * d2v - ajz * d1);
        float t1 = 2.f * (ajz * d0 - ajx * d2v);
        float t2 = 2.f * (ajx * d1 - ajy * d0);
        float lx0 = d0 + ajw * t0 + (ajy * t2 - ajz * t1);
        float lx1 = d1 + ajw * t1 + (ajz * t0 - ajx * t2);
        float lx2 = d2v + ajw * t2 + (ajx * t1 - ajy * t0);
        float lqw = ajw * qi0 - ajx * qi1 - ajy * qi2 - ajz * qi3;
        float lqx = ajw * qi1 + ajx * qi0 + ajy * qi3 - ajz * qi2;
        float lqy = ajw * qi2 - ajx * qi3 + ajy * qi0 + ajz * qi1;
        float lqz = ajw * qi3 + ajx * qi2 - ajy * qi1 + ajz * qi0;
        float nn2 = qj.x * qj.x + qj.y * qj.y + qj.z * qj.z + qj.w * qj.w;
        float rn = 1.f / fmaxf(sqrtf(nn2), 1e-12f);
        nqw = qj.x * rn; nqx = qj.y * rn; nqy = qj.z * rn; nqz = qj.w * rn;
        uint4 g0, g1;
        g0.x = pk2(lx0, lx1); g0.y = pk2(lx2, lqw);
        g0.z = pk2(lqx, lqy); g0.w = pk2(lqz, d2);
        g1.x = pk2(qdot, 0.f); g1.y = 0; g1.z = 0; g1.w = 0;
        *(uint4*)&sFw[lane * 136 + 32] = g0;
        *(uint4*)&sFw[lane * 136 + 40] = g1;
      }
    }

    // ---- layer 1: a1 = relu(F@W1 + (Hi broadcast)) ----
    f32x4 acc[4];
#pragma unroll
    for (int nt = 0; nt < 4; ++nt)
      acc[nt] = (f32x4){HiF[nt], HiF[nt], HiF[nt], HiF[nt]};
#pragma unroll
    for (int ks = 0; ks < 4; ++ks) {
      short8 af = *(const short8*)&sFw[nl * 136 + ks * 32 + quad * 8];
#pragma unroll
      for (int nt = 0; nt < 4; ++nt)
        acc[nt] = __builtin_amdgcn_mfma_f32_16x16x32_bf16(af, W1f[nt][ks], acc[nt], 0, 0, 0);
    }
#pragma unroll
    for (int nt = 0; nt < 4; ++nt)
#pragma unroll
      for (int r = 0; r < 4; ++r)
        sTw[(quad * 4 + r) * 72 + nt * 16 + nl] = f2bf(fmaxf(acc[nt][r], 0.f));

    // ---- layer 2: m = a1@W2 + bm2, mask j==i, accumulate msum ----
#pragma unroll
    for (int nt = 0; nt < 4; ++nt)
      acc[nt] = (f32x4){bm2F[nt], bm2F[nt], bm2F[nt], bm2F[nt]};
#pragma unroll
    for (int ks = 0; ks < 2; ++ks) {
      short8 af = *(const short8*)&sTw[nl * 72 + ks * 32 + quad * 8];
#pragma unroll
      for (int nt = 0; nt < 4; ++nt)
        acc[nt] = __builtin_amdgcn_mfma_f32_16x16x32_bf16(af, W2f[nt][ks], acc[nt], 0, 0, 0);
    }
#pragma unroll
    for (int nt = 0; nt < 4; ++nt)
#pragma unroll
      for (int r = 0; r < 4; ++r) {
        int row = quad * 4 + r;
        float v = acc[nt][r];
        if (jb + row == i) v = 0.f;
        msum[nt][r] += v;
        sTw[row * 72 + nt * 16 + nl] = f2bf(v);
      }

    // ---- dx layer 1: x1 = relu(m@Wx1 + bx1) ----
#pragma unroll
    for (int nt = 0; nt < 4; ++nt)
      acc[nt] = (f32x4){bx1F[nt], bx1F[nt], bx1F[nt], bx1F[nt]};
#pragma unroll
    for (int ks = 0; ks < 2; ++ks) {
      short8 af = *(const short8*)&sTw[nl * 72 + ks * 32 + quad * 8];
#pragma unroll
      for (int nt = 0; nt < 4; ++nt)
        acc[nt] = __builtin_amdgcn_mfma_f32_16x16x32_bf16(af, Wx1f[nt][ks], acc[nt], 0, 0, 0);
    }
#pragma unroll
    for (int nt = 0; nt < 4; ++nt)
#pragma unroll
      for (int r = 0; r < 4; ++r)
        sTw[(quad * 4 + r) * 72 + nt * 16 + nl] = f2bf(fmaxf(acc[nt][r], 0.f));

    // ---- dx layer 2: dx = x1@Wx2 + bx2 (cols 0..2) ----
    f32x4 dacc = (f32x4){bx2F, bx2F, bx2F, bx2F};
#pragma unroll
    for (int ks = 0; ks < 2; ++ks) {
      short8 af = *(const short8*)&sTw[nl * 72 + ks * 32 + quad * 8];
      dacc = __builtin_amdgcn_mfma_f32_16x16x32_bf16(af, Wx2f[ks], dacc, 0, 0, 0);
    }
    if (nl < 3) {
#pragma unroll
      for (int r = 0; r < 4; ++r) sDxT[wid][quad * 4 + r][nl] = dacc[r];
    }
    // rotate by normalized q_j and accumulate (lanes 0..15; nq held from geo phase)
    if (lane < 16) {
      int j = jb + lane;
      if (j != i) {
        float dxc0 = sDxT[wid][lane][0];
        float dxc1 = sDxT[wid][lane][1];
        float dxc2 = sDxT[wid][lane][2];
        float rt0 = 2.f * (nqy * dxc2 - nqz * dxc1);
        float rt1 = 2.f * (nqz * dxc0 - nqx * dxc2);
        float rt2 = 2.f * (nqx * dxc1 - nqy * dxc0);
        dxs0 += dxc0 + nqw * rt0 + (nqy * rt2 - nqz * rt1);
        dxs1 += dxc1 + nqw * rt1 + (nqz * rt0 - nqx * rt2);
        dxs2 += dxc2 + nqw * rt2 + (nqx * rt1 - nqy * rt0);
      }
    }
  }

  // ---- per-wave reductions ----
#pragma unroll
  for (int nt = 0; nt < 4; ++nt) {
    float s = msum[nt][0] + msum[nt][1] + msum[nt][2] + msum[nt][3];
    s += __shfl_xor(s, 16);
    s += __shfl_xor(s, 32);
    if (lane < 16) sMsum[wid][nt * 16 + lane] = s;
  }
  {
    float a = dxs0, bb = dxs1, cc = dxs2;
#pragma unroll
    for (int off = 1; off < 16; off <<= 1) {
      a += __shfl_xor(a, off);
      bb += __shfl_xor(bb, off);
      cc += __shfl_xor(cc, off);
    }
    if (lane == 0) { sDx[wid][0] = a; sDx[wid][1] = bb; sDx[wid][2] = cc; }
  }
  __syncthreads();

  // ---- phase 3: per-node epilogues, one wave each ----
  if (wid == 0) {
    float ms = sMsum[0][lane] + sMsum[1][lane] + sMsum[2][lane] + sMsum[3][lane];
    sPh3[0][lane] = ms;
    float f1a = bf1[lane], f1b = 0.f;
#pragma unroll 8
    for (int k = 0; k < 64; ++k) {
      f1a += sHi64[k] * Wf1[k * 64 + lane];
      f1b += sPh3[0][k] * Wf1[(64 + k) * 64 + lane];
    }
    float f1 = fmaxf(f1a + f1b, 0.f);
    sPh3[0][lane] = f1;
    float oacc = bf2_[lane];
#pragma unroll 8
    for (int k = 0; k < 64; ++k) oacc += sPh3[0][k] * Wf2[k * 64 + lane];
    out[OFF_O + node * 64 + lane] = oacc;
  } else if (wid == 1) {
    float ms = sMsum[0][lane] + sMsum[1][lane] + sMsum[2][lane] + sMsum[3][lane];
    sPh3[1][lane] = ms;
    float a = bq1[lane];
#pragma unroll 8
    for (int k = 0; k < 64; ++k) a += sPh3[1][k] * Wq1[k * 64 + lane];
    a = fmaxf(a, 0.f);
    float p0 = a * Wq2[lane * 4 + 0];
    float p1 = a * Wq2[lane * 4 + 1];
    float p2 = a * Wq2[lane * 4 + 2];
    float p3 = a * Wq2[lane * 4 + 3];
#pragma unroll
    for (int off = 32; off >= 1; off >>= 1) {
      p0 += __shfl_xor(p0, off);
      p1 += __shfl_xor(p1, off);
      p2 += __shfl_xor(p2, off);
      p3 += __shfl_xor(p3, off);
    }
    float dq0 = p0 + bq2[0], dq1 = p1 + bq2[1];
    float dq2 = p2 + bq2[2], dq3 = p3 + bq2[3];
    float n = fmaxf(sqrtf(dq0 * dq0 + dq1 * dq1 + dq2 * dq2 + dq3 * dq3), 1e-12f);
    dq0 /= n; dq1 /= n; dq2 /= n; dq3 /= n;
    float uw = qi0 * dq0 - qi1 * dq1 - qi2 * dq2 - qi3 * dq3;
    float ux = qi0 * dq1 + qi1 * dq0 + qi2 * dq3 - qi3 * dq2;
    float uy = qi0 * dq2 - qi1 * dq3 + qi2 * dq0 + qi3 * dq1;
    float uz = qi0 * dq3 + qi1 * dq2 - qi2 * dq1 + qi3 * dq0;
    float n2 = fmaxf(sqrtf(uw * uw + ux * ux + uy * uy + uz * uz), 1e-12f);
    if (lane == 0) {
      float* po = out + OFF_Q + node * 4;
      po[0] = uw / n2; po[1] = ux / n2; po[2] = uy / n2; po[3] = uz / n2;
    }
  } else if (wid == 2) {
    float ms = sMsum[0][lane] + sMsum[1][lane] + sMsum[2][lane] + sMsum[3][lane];
    sPh3[2][lane] = ms;
    float a = bt1[lane];
#pragma unroll 8
    for (int k = 0; k < 64; ++k) a += sPh3[2][k] * Wt1[k * 64 + lane];
    a = fmaxf(a, 0.f);
    sPh3[2][lane] = a;
    if (lane < 14) {
      float v = bt2[lane];
#pragma unroll 8
      for (int k = 0; k < 64; ++k) v += sPh3[2][k] * Wt2[k * 14 + lane];
      float pv = __shfl_xor(v, 1);
      float nrm = fmaxf(sqrtf(v * v + pv * pv), 1e-12f);
      out[OFF_T + node * 14 + lane] = v / nrm;
    }
  } else {
    if (lane < 3) {
      float xs = sDx[0][lane] + sDx[1][lane] + sDx[2][lane] + sDx[3][lane];
      float xiv = (lane == 0) ? xi0 : (lane == 1) ? xi1 : xi2;
      out[OFF_X + node * 3 + lane] = xiv + xs / 639.0f;
    }
  }
}

extern "C" void kernel_launch(void* const* d_in, const int* in_sizes, int n_in,
                              void* d_out, int out_size, void* d_ws, size_t ws_size,
                              hipStream_t stream) {
  const float* q   = (const float*)d_in[0];
  const float* x   = (const float*)d_in[1];
  const float* h   = (const float*)d_in[3];
  const float* e   = (const float*)d_in[4];
  const float* pq  = (const float*)d_in[6];
  const float* px  = (const float*)d_in[7];
  const float* pe  = (const float*)d_in[8];
  const float* ph  = (const float*)d_in[9];
  const float* Wm1 = (const float*)d_in[11];
  const float* bm1 = (const float*)d_in[12];
  const float* Wm2 = (const float*)d_in[13];
  const float* bm2 = (const float*)d_in[14];
  const float* Wf1 = (const float*)d_in[15];
  const float* bf1 = (const float*)d_in[16];
  const float* Wf2 = (const float*)d_in[17];
  const float* bf2_ = (const float*)d_in[18];
  const float* Wx1 = (const float*)d_in[19];
  const float* bx1 = (const float*)d_in[20];
  const float* Wx2 = (const float*)d_in[21];
  const float* bx2 = (const float*)d_in[22];
  const float* Wq1 = (const float*)d_in[23];
  const float* bq1 = (const float*)d_in[24];
  const float* Wq2 = (const float*)d_in[25];
  const float* bq2 = (const float*)d_in[26];
  const float* Wt1 = (const float*)d_in[27];
  const float* bt1 = (const float*)d_in[28];
  const float* Wt2 = (const float*)d_in[29];
  const float* bt2 = (const float*)d_in[30];

  egnn_fused<<<NB * NN, 256, 0, stream>>>(
      q, x, h, e, pe, pq, px, ph,
      Wm1, bm1, Wm2, bm2, Wx1, bx1, Wx2, bx2,
      Wf1, bf1, Wf2, bf2_, Wq1, bq1, Wq2, bq2,
      Wt1, bt1, Wt2, bt2, (float*)d_out);
}

// Round 5
// 186.938 us; speedup vs baseline: 2.8398x; 1.1920x over previous
//
#include <hip/hip_runtime.h>
#include <stdint.h>

#define NB 4
#define NN 128
#define NP 512
#define NJ 640
#define HD 64
#define ED 32

typedef unsigned short u16;
typedef __attribute__((ext_vector_type(8))) short short8;
typedef __attribute__((ext_vector_type(4))) float f32x4;

// out element offsets (f32): upd_q[2048], upd_x[1536], tor[7168], o[32768]
#define OFF_Q 0
#define OFF_X 2048
#define OFF_T 3584
#define OFF_O 10752

__device__ __forceinline__ u16 f2bf(float f) {
  union { float f; uint32_t i; } v; v.f = f;
  uint32_t x = v.i;
  return (u16)((x + 0x7FFFu + ((x >> 16) & 1u)) >> 16);
}
__device__ __forceinline__ uint32_t pk2(float a, float b) {
  return (uint32_t)f2bf(a) | ((uint32_t)f2bf(b) << 16);
}

// feature k (0..127) -> Wm1 row, or -1 for zero-pad
__device__ __forceinline__ int w1row(int k) {
  if (k < 32) return 128 + k;          // e
  if (k < 35) return 160 + (k - 32);   // local_x
  if (k < 39) return 163 + (k - 35);   // local_q
  if (k == 39) return 167;             // d2
  if (k == 40) return 168;             // qdot
  if (k < 48) return -1;               // pad
  if (k < 112) return 64 + (k - 48);   // h_j
  return -1;                           // pad
}

// One block per (b,i). 4 waves, 10 edge-tiles of 16 each.
// F layout (bf16, 136-short rows): k0..31=e, k32..40=geo, k41..47=0,
// k48..111=h_j, k112..127=0.
__global__ void __launch_bounds__(256, 1)
egnn_fused(const float* __restrict__ q, const float* __restrict__ x,
           const float* __restrict__ h, const float* __restrict__ e,
           const float* __restrict__ pe, const float* __restrict__ pq,
           const float* __restrict__ px, const float* __restrict__ ph,
           const float* __restrict__ Wm1, const float* __restrict__ bm1,
           const float* __restrict__ Wm2, const float* __restrict__ bm2,
           const float* __restrict__ Wx1, const float* __restrict__ bx1,
           const float* __restrict__ Wx2, const float* __restrict__ bx2,
           const float* __restrict__ Wf1, const float* __restrict__ bf1,
           const float* __restrict__ Wf2, const float* __restrict__ bf2_,
           const float* __restrict__ Wq1, const float* __restrict__ bq1,
           const float* __restrict__ Wq2, const float* __restrict__ bq2,
           const float* __restrict__ Wt1, const float* __restrict__ bt1,
           const float* __restrict__ Wt2, const float* __restrict__ bt2,
           float* __restrict__ out)
{
  __shared__ u16 sW1B[64 * 136];      // W1 bf16, [n][k] k-contiguous
  __shared__ u16 sW2B[64 * 72];       // W2 bf16, [n][k]
  __shared__ u16 sWx1B[64 * 72];      // Wx1 bf16, [n][k]
  __shared__ u16 sWx2B[16 * 72];      // Wx2 bf16, [n][k], n>=3 zero
  __shared__ u16 sF[4][16 * 136];     // per-wave feature tile
  __shared__ u16 sT[4][16 * 72];      // per-wave a1/m/x1 transform buffer
  __shared__ float sDxT[4][16][4];
  __shared__ float sMsum[4][64];
  __shared__ float sDx[4][3];
  __shared__ float sHi64[64];
  __shared__ float sHiP[64];          // Hi = h_i@Wm1[0:64]+bm1
  __shared__ float sPh3[4][64];

  const int b = blockIdx.x >> 7;
  const int i = blockIdx.x & 127;
  const int tid = threadIdx.x;
  const int wid = tid >> 6;
  const int lane = tid & 63;
  const int nl = lane & 15;
  const int quad = lane >> 4;
  const size_t node = (size_t)(b * NN + i);

  u16* sFw = sF[wid];
  u16* sTw = sT[wid];

  // ---- stage weights to LDS (bf16, B-fragment-friendly [n][k]) ----
  for (int idx = tid; idx < 64 * 128; idx += 256) {
    int n = idx >> 7, k = idx & 127;
    int row = w1row(k);
    sW1B[n * 136 + k] = (row < 0) ? (u16)0 : f2bf(Wm1[(size_t)row * 64 + n]);
  }
  for (int idx = tid; idx < 64 * 64; idx += 256) {
    int n = idx >> 6, k = idx & 63;
    sW2B[n * 72 + k]  = f2bf(Wm2[(size_t)k * 64 + n]);
    sWx1B[n * 72 + k] = f2bf(Wx1[(size_t)k * 64 + n]);
  }
  for (int idx = tid; idx < 16 * 64; idx += 256) {
    int n = idx >> 6, k = idx & 63;
    sWx2B[n * 72 + k] = (n < 3) ? f2bf(Wx2[(size_t)k * 3 + n]) : (u16)0;
  }
  // zero own F pad region (live regions rewritten per tile)
  for (int idx = lane; idx < 16 * 136 / 2; idx += 64) ((uint32_t*)sFw)[idx] = 0;

  if (tid < 64) sHi64[tid] = h[node * HD + tid];
  if (tid >= 64 && tid < 128) {
    int col = tid - 64;
    float acc = bm1[col];
#pragma unroll 8
    for (int k = 0; k < HD; ++k) acc += h[node * HD + k] * Wm1[k * 64 + col];
    sHiP[col] = acc;
  }

  const float* qr0 = q + node * 4;
  const float qi0 = qr0[0], qi1 = qr0[1], qi2 = qr0[2], qi3 = qr0[3];
  const float* xr0 = x + node * 3;
  const float xi0 = xr0[0], xi1 = xr0[1], xi2 = xr0[2];

  __syncthreads();  // weights + sHiP ready

  // ---- small weight fragments in registers (18 short8 = 72 VGPRs) ----
  short8 W2f[4][2], Wx1f[4][2], Wx2f[2];
#pragma unroll
  for (int nt = 0; nt < 4; ++nt)
#pragma unroll
    for (int ks = 0; ks < 2; ++ks) {
      W2f[nt][ks]  = *(const short8*)&sW2B[(nt * 16 + nl) * 72 + ks * 32 + quad * 8];
      Wx1f[nt][ks] = *(const short8*)&sWx1B[(nt * 16 + nl) * 72 + ks * 32 + quad * 8];
    }
#pragma unroll
  for (int ks = 0; ks < 2; ++ks)
    Wx2f[ks] = *(const short8*)&sWx2B[nl * 72 + ks * 32 + quad * 8];

  float HiF[4], bm2F[4], bx1F[4];
#pragma unroll
  for (int nt = 0; nt < 4; ++nt) {
    HiF[nt] = sHiP[nt * 16 + nl];
    bm2F[nt] = bm2[nt * 16 + nl];
    bx1F[nt] = bx1[nt * 16 + nl];
  }
  const float bx2F = (nl < 3) ? bx2[nl] : 0.f;

  f32x4 msum[4];
#pragma unroll
  for (int nt = 0; nt < 4; ++nt) msum[nt] = (f32x4){0.f, 0.f, 0.f, 0.f};
  float dxs0 = 0.f, dxs1 = 0.f, dxs2 = 0.f;
  float nqw = 0.f, nqx = 0.f, nqy = 0.f, nqz = 0.f;

  for (int tile = wid; tile < 40; tile += 4) {
    const int jb = tile * 16;
    // ---- build F (wave-private LDS; no block barrier needed) ----
    {
      int er = lane >> 2, c = lane & 3;
      int jr = jb + er;
      const float* ebase = (jr < NN)
          ? e + ((node * NN) + jr) * ED + c * 8
          : pe + ((node * NP) + (jr - NN)) * ED + c * 8;
      float4 e0 = *(const float4*)ebase;
      float4 e1 = *(const float4*)(ebase + 4);
      uint4 pw;
      pw.x = pk2(e0.x, e0.y); pw.y = pk2(e0.z, e0.w);
      pw.z = pk2(e1.x, e1.y); pw.w = pk2(e1.z, e1.w);
      *(uint4*)&sFw[er * 136 + c * 8] = pw;

      const float* hb = (jr < NN) ? h + ((size_t)(b * NN + jr)) * HD + c * 16
                                  : ph + ((size_t)(b * NP + (jr - NN))) * HD + c * 16;
      float4 h0 = *(const float4*)hb, h1 = *(const float4*)(hb + 4);
      float4 h2 = *(const float4*)(hb + 8), h3 = *(const float4*)(hb + 12);
      uint4 pa, pb;
      pa.x = pk2(h0.x, h0.y); pa.y = pk2(h0.z, h0.w);
      pa.z = pk2(h1.x, h1.y); pa.w = pk2(h1.z, h1.w);
      pb.x = pk2(h2.x, h2.y); pb.y = pk2(h2.z, h2.w);
      pb.z = pk2(h3.x, h3.y); pb.w = pk2(h3.z, h3.w);
      *(uint4*)&sFw[er * 136 + 48 + c * 16] = pa;
      *(uint4*)&sFw[er * 136 + 56 + c * 16] = pb;

      if (lane < 16) {
        int j = jb + lane;
        const float* qr = (j < NN) ? q + ((size_t)(b * NN + j)) * 4
                                   : pq + ((size_t)(b * NP + (j - NN))) * 4;
        float4 qj = *(const float4*)qr;
        const float* xr = (j < NN) ? x + ((size_t)(b * NN + j)) * 3
                                   : px + ((size_t)(b * NP + (j - NN))) * 3;
        float xj0 = xr[0], xj1 = xr[1], xj2 = xr[2];
        float d0 = xi0 - xj0, d1 = xi1 - xj1, d2v = xi2 - xj2;
        float d2 = d0 * d0 + d1 * d1 + d2v * d2v;
        float qdot = fabsf(qi0 * qj.x + qi1 * qj.y + qi2 * qj.z + qi3 * qj.w);
        float ajw = qj.x, ajx = -qj.y, ajy = -qj.z, ajz = -qj.w;  // conj
        float t0 = 2.f * (ajy * d2v - ajz * d1);
        float t1 = 2.f * (ajz * d0 - ajx * d2v);
        float t2 = 2.f * (ajx * d1 - ajy * d0);
        float lx0 = d0 + ajw * t0 + (ajy * t2 - ajz * t1);
        float lx1 = d1 + ajw * t1 + (ajz * t0 - ajx * t2);
        float lx2 = d2v + ajw * t2 + (ajx * t1 - ajy * t0);
        float lqw = ajw * qi0 - ajx * qi1 - ajy * qi2 - ajz * qi3;
        float lqx = ajw * qi1 + ajx * qi0 + ajy * qi3 - ajz * qi2;
        float lqy = ajw * qi2 - ajx * qi3 + ajy * qi0 + ajz * qi1;
        float lqz = ajw * qi3 + ajx * qi2 - ajy * qi1 + ajz * qi0;
        float nn2 = qj.x * qj.x + qj.y * qj.y + qj.z * qj.z + qj.w * qj.w;
        float rn = 1.f / fmaxf(sqrtf(nn2), 1e-12f);
        nqw = qj.x * rn; nqx = qj.y * rn; nqy = qj.z * rn; nqz = qj.w * rn;
        uint4 g0, g1;
        g0.x = pk2(lx0, lx1); g0.y = pk2(lx2, lqw);
        g0.z = pk2(lqx, lqy); g0.w = pk2(lqz, d2);
        g1.x = pk2(qdot, 0.f); g1.y = 0; g1.z = 0; g1.w = 0;
        *(uint4*)&sFw[lane * 136 + 32] = g0;
        *(uint4*)&sFw[lane * 136 + 40] = g1;
      }
    }

    // ---- layer 1: a1 = relu(F@W1 + (Hi broadcast)); W1 B-frags from LDS ----
    f32x4 acc[4];
#pragma unroll
    for (int nt = 0; nt < 4; ++nt)
      acc[nt] = (f32x4){HiF[nt], HiF[nt], HiF[nt], HiF[nt]};
#pragma unroll
    for (int ks = 0; ks < 4; ++ks) {
      short8 af = *(const short8*)&sFw[nl * 136 + ks * 32 + quad * 8];
#pragma unroll
      for (int nt = 0; nt < 4; ++nt) {
        short8 bfr = *(const short8*)&sW1B[(nt * 16 + nl) * 136 + ks * 32 + quad * 8];
        acc[nt] = __builtin_amdgcn_mfma_f32_16x16x32_bf16(af, bfr, acc[nt], 0, 0, 0);
      }
    }
#pragma unroll
    for (int nt = 0; nt < 4; ++nt)
#pragma unroll
      for (int r = 0; r < 4; ++r)
        sTw[(quad * 4 + r) * 72 + nt * 16 + nl] = f2bf(fmaxf(acc[nt][r], 0.f));

    // ---- layer 2: m = a1@W2 + bm2, mask j==i, accumulate msum ----
#pragma unroll
    for (int nt = 0; nt < 4; ++nt)
      acc[nt] = (f32x4){bm2F[nt], bm2F[nt], bm2F[nt], bm2F[nt]};
#pragma unroll
    for (int ks = 0; ks < 2; ++ks) {
      short8 af = *(const short8*)&sTw[nl * 72 + ks * 32 + quad * 8];
#pragma unroll
      for (int nt = 0; nt < 4; ++nt)
        acc[nt] = __builtin_amdgcn_mfma_f32_16x16x32_bf16(af, W2f[nt][ks], acc[nt], 0, 0, 0);
    }
#pragma unroll
    for (int nt = 0; nt < 4; ++nt)
#pragma unroll
      for (int r = 0; r < 4; ++r) {
        int row = quad * 4 + r;
        float v = acc[nt][r];
        if (jb + row == i) v = 0.f;
        msum[nt][r] += v;
        sTw[row * 72 + nt * 16 + nl] = f2bf(v);
      }

    // ---- dx layer 1: x1 = relu(m@Wx1 + bx1) ----
#pragma unroll
    for (int nt = 0; nt < 4; ++nt)
      acc[nt] = (f32x4){bx1F[nt], bx1F[nt], bx1F[nt], bx1F[nt]};
#pragma unroll
    for (int ks = 0; ks < 2; ++ks) {
      short8 af = *(const short8*)&sTw[nl * 72 + ks * 32 + quad * 8];
#pragma unroll
      for (int nt = 0; nt < 4; ++nt)
        acc[nt] = __builtin_amdgcn_mfma_f32_16x16x32_bf16(af, Wx1f[nt][ks], acc[nt], 0, 0, 0);
    }
#pragma unroll
    for (int nt = 0; nt < 4; ++nt)
#pragma unroll
      for (int r = 0; r < 4; ++r)
        sTw[(quad * 4 + r) * 72 + nt * 16 + nl] = f2bf(fmaxf(acc[nt][r], 0.f));

    // ---- dx layer 2: dx = x1@Wx2 + bx2 (cols 0..2) ----
    f32x4 dacc = (f32x4){bx2F, bx2F, bx2F, bx2F};
#pragma unroll
    for (int ks = 0; ks < 2; ++ks) {
      short8 af = *(const short8*)&sTw[nl * 72 + ks * 32 + quad * 8];
      dacc = __builtin_amdgcn_mfma_f32_16x16x32_bf16(af, Wx2f[ks], dacc, 0, 0, 0);
    }
    if (nl < 3) {
#pragma unroll
      for (int r = 0; r < 4; ++r) sDxT[wid][quad * 4 + r][nl] = dacc[r];
    }
    // rotate by normalized q_j and accumulate (lanes 0..15; nq held from geo phase)
    if (lane < 16) {
      int j = jb + lane;
      if (j != i) {
        float dxc0 = sDxT[wid][lane][0];
        float dxc1 = sDxT[wid][lane][1];
        float dxc2 = sDxT[wid][lane][2];
        float rt0 = 2.f * (nqy * dxc2 - nqz * dxc1);
        float rt1 = 2.f * (nqz * dxc0 - nqx * dxc2);
        float rt2 = 2.f * (nqx * dxc1 - nqy * dxc0);
        dxs0 += dxc0 + nqw * rt0 + (nqy * rt2 - nqz * rt1);
        dxs1 += dxc1 + nqw * rt1 + (nqz * rt0 - nqx * rt2);
        dxs2 += dxc2 + nqw * rt2 + (nqx * rt1 - nqy * rt0);
      }
    }
  }

  // ---- per-wave reductions ----
#pragma unroll
  for (int nt = 0; nt < 4; ++nt) {
    float s = msum[nt][0] + msum[nt][1] + msum[nt][2] + msum[nt][3];
    s += __shfl_xor(s, 16);
    s += __shfl_xor(s, 32);
    if (lane < 16) sMsum[wid][nt * 16 + lane] = s;
  }
  {
    float a = dxs0, bb = dxs1, cc = dxs2;
#pragma unroll
    for (int off = 1; off < 16; off <<= 1) {
      a += __shfl_xor(a, off);
      bb += __shfl_xor(bb, off);
      cc += __shfl_xor(cc, off);
    }
    if (lane == 0) { sDx[wid][0] = a; sDx[wid][1] = bb; sDx[wid][2] = cc; }
  }
  __syncthreads();

  // ---- phase 3: per-node epilogues, one wave each ----
  if (wid == 0) {
    float ms = sMsum[0][lane] + sMsum[1][lane] + sMsum[2][lane] + sMsum[3][lane];
    sPh3[0][lane] = ms;
    float f1a = bf1[lane], f1b = 0.f;
#pragma unroll 8
    for (int k = 0; k < 64; ++k) {
      f1a += sHi64[k] * Wf1[k * 64 + lane];
      f1b += sPh3[0][k] * Wf1[(64 + k) * 64 + lane];
    }
    float f1 = fmaxf(f1a + f1b, 0.f);
    sPh3[0][lane] = f1;
    float oacc = bf2_[lane];
#pragma unroll 8
    for (int k = 0; k < 64; ++k) oacc += sPh3[0][k] * Wf2[k * 64 + lane];
    out[OFF_O + node * 64 + lane] = oacc;
  } else if (wid == 1) {
    float ms = sMsum[0][lane] + sMsum[1][lane] + sMsum[2][lane] + sMsum[3][lane];
    sPh3[1][lane] = ms;
    float a = bq1[lane];
#pragma unroll 8
    for (int k = 0; k < 64; ++k) a += sPh3[1][k] * Wq1[k * 64 + lane];
    a = fmaxf(a, 0.f);
    float p0 = a * Wq2[lane * 4 + 0];
    float p1 = a * Wq2[lane * 4 + 1];
    float p2 = a * Wq2[lane * 4 + 2];
    float p3 = a * Wq2[lane * 4 + 3];
#pragma unroll
    for (int off = 32; off >= 1; off >>= 1) {
      p0 += __shfl_xor(p0, off);
      p1 += __shfl_xor(p1, off);
      p2 += __shfl_xor(p2, off);
      p3 += __shfl_xor(p3, off);
    }
    float dq0 = p0 + bq2[0], dq1 = p1 + bq2[1];
    float dq2 = p2 + bq2[2], dq3 = p3 + bq2[3];
    float n = fmaxf(sqrtf(dq0 * dq0 + dq1 * dq1 + dq2 * dq2 + dq3 * dq3), 1e-12f);
    dq0 /= n; dq1 /= n; dq2 /= n; dq3 /= n;
    float uw = qi0 * dq0 - qi1 * dq1 - qi2 * dq2 - qi3 * dq3;
    float ux = qi0 * dq1 + qi1 * dq0 + qi2 * dq3 - qi3 * dq2;
    float uy = qi0 * dq2 - qi1 * dq3 + qi2 * dq0 + qi3 * dq1;
    float uz = qi0 * dq3 + qi1 * dq2 - qi2 * dq1 + qi3 * dq0;
    float n2 = fmaxf(sqrtf(uw * uw + ux * ux + uy * uy + uz * uz), 1e-12f);
    if (lane == 0) {
      float* po = out + OFF_Q + node * 4;
      po[0] = uw / n2; po[1] = ux / n2; po[2] = uy / n2; po[3] = uz / n2;
    }
  } else if (wid == 2) {
    float ms = sMsum[0][lane] + sMsum[1][lane] + sMsum[2][lane] + sMsum[3][lane];
    sPh3[2][lane] = ms;
    float a = bt1[lane];
#pragma unroll 8
    for (int k = 0; k < 64; ++k) a += sPh3[2][k] * Wt1[k * 64 + lane];
    a = fmaxf(a, 0.f);
    sPh3[2][lane] = a;
    if (lane < 14) {
      float v = bt2[lane];
#pragma unroll 8
      for (int k = 0; k < 64; ++k) v += sPh3[2][k] * Wt2[k * 14 + lane];
      float pv = __shfl_xor(v, 1);
      float nrm = fmaxf(sqrtf(v * v + pv * pv), 1e-12f);
      out[OFF_T + node * 14 + lane] = v / nrm;
    }
  } else {
    if (lane < 3) {
      float xs = sDx[0][lane] + sDx[1][lane] + sDx[2][lane] + sDx[3][lane];
      float xiv = (lane == 0) ? xi0 : (lane == 1) ? xi1 : xi2;
      out[OFF_X + node * 3 + lane] = xiv + xs / 639.0f;
    }
  }
}

extern "C" void kernel_launch(void* const* d_in, const int* in_sizes, int n_in,
                              void* d_out, int out_size, void* d_ws, size_t ws_size,
                              hipStream_t stream) {
  const float* q   = (const float*)d_in[0];
  const float* x   = (const float*)d_in[1];
  const float* h   = (const float*)d_in[3];
  const float* e   = (const float*)d_in[4];
  const float* pq  = (const float*)d_in[6];
  const float* px  = (const float*)d_in[7];
  const float* pe  = (const float*)d_in[8];
  const float* ph  = (const float*)d_in[9];
  const float* Wm1 = (const float*)d_in[11];
  const float* bm1 = (const float*)d_in[12];
  const float* Wm2 = (const float*)d_in[13];
  const float* bm2 = (const float*)d_in[14];
  const float* Wf1 = (const float*)d_in[15];
  const float* bf1 = (const float*)d_in[16];
  const float* Wf2 = (const float*)d_in[17];
  const float* bf2_ = (const float*)d_in[18];
  const float* Wx1 = (const float*)d_in[19];
  const float* bx1 = (const float*)d_in[20];
  const float* Wx2 = (const float*)d_in[21];
  const float* bx2 = (const float*)d_in[22];
  const float* Wq1 = (const float*)d_in[23];
  const float* bq1 = (const float*)d_in[24];
  const float* Wq2 = (const float*)d_in[25];
  const float* bq2 = (const float*)d_in[26];
  const float* Wt1 = (const float*)d_in[27];
  const float* bt1 = (const float*)d_in[28];
  const float* Wt2 = (const float*)d_in[29];
  const float* bt2 = (const float*)d_in[30];

  egnn_fused<<<NB * NN, 256, 0, stream>>>(
      q, x, h, e, pe, pq, px, ph,
      Wm1, bm1, Wm2, bm2, Wx1, bx1, Wx2, bx2,
      Wf1, bf1, Wf2, bf2_, Wq1, bq1, Wq2, bq2,
      Wt1, bt1, Wt2, bt2, (float*)d_out);
}